// Round 6
// baseline (380.345 us; speedup 1.0000x reference)
//
#include <hip/hip_runtime.h>
#include <hip/hip_bf16.h>
#include <hip/hip_cooperative_groups.h>

namespace cg = cooperative_groups;

#define D_DIM 1024
#define C_CLS 64
#define N_SUP 4096
#define M_Q   8192
#define NBLK  512
#define LMAX  320
#define LDA   136
#define KQ    256

typedef __attribute__((ext_vector_type(8))) short short8;
typedef __attribute__((ext_vector_type(4))) float f32x4;

__device__ inline unsigned short f2bf(float x) {
    __hip_bfloat16 h = __float2bfloat16(x);
    return __builtin_bit_cast(unsigned short, h);
}

// ---------------- fused cooperative kernel: ~17.7 KB LDS ----------------
union SharedU {
    struct {                      // stage 2
        int   lst[LMAX];          // 1.25 KB
        float rvs[LMAX];          // 1.25 KB
        float PP[2][128];         // 1 KB
    } s2;
    union {                       // stage 3 (A and P time-share)
        unsigned short A[4][16 * LDA];                  // 17.0 KB, wave-private
        struct { float P[4][16][64]; float rinvR[16]; } e;  // 16.1 KB
    } s3;
};

__global__ __launch_bounds__(256, 2) void k_fused(const float* __restrict__ gS,
                                                  const float* __restrict__ fX,
                                                  const int* __restrict__ tgt,
                                                  float* __restrict__ rinv,
                                                  unsigned short* __restrict__ Wb,
                                                  float* __restrict__ out) {
    __shared__ SharedU sm;
    __shared__ int cnt;
    __shared__ float SSred[4][16];
    cg::grid_group grid = cg::this_grid();

    const int t = threadIdx.x;
    const int w = t >> 6, l = t & 63;
    const int bid = blockIdx.x;
    if (t == 0) cnt = 0;

    // issue stage-3 fX loads now; values land in VGPRs during stages 1-2
    const int m0 = bid * 16;
    const float* Ab = fX + (size_t)m0 * D_DIM + w * KQ;
    float4 ld0[8], ld1[8];
#pragma unroll
    for (int j = 0; j < 8; ++j) {
        const int f = l + 64 * j, r = f >> 5, c4 = f & 31;
        ld0[j] = reinterpret_cast<const float4*>(Ab + (size_t)r * D_DIM)[c4];
        ld1[j] = reinterpret_cast<const float4*>(Ab + (size_t)r * D_DIM + 128)[c4];
    }

    // ---- stage 1: rinv[n], 8 rows/block, 2 rows/wave ----
#pragma unroll
    for (int rr = 0; rr < 2; ++rr) {
        const int n = bid * 8 + w * 2 + rr;
        const float4* R = reinterpret_cast<const float4*>(gS + (size_t)n * D_DIM);
        float ss = 0.f;
#pragma unroll
        for (int q = 0; q < 4; ++q) {
            const float4 v = R[l + 64 * q];
            ss += v.x * v.x + v.y * v.y + v.z * v.z + v.w * v.w;
        }
#pragma unroll
        for (int off = 32; off > 0; off >>= 1)
            ss += __shfl_xor(ss, off, 64);
        if (l == 0) rinv[n] = rsqrtf(fmaxf(ss, 1e-24f));
    }
    __threadfence();
    grid.sync();
    __threadfence();

    // ---- stage 2: Wb[c][d0+0..127], 512 blocks = 64 classes x 8 chunks ----
    {
        const int c  = bid >> 3;
        const int d0 = (bid & 7) * 128;
        for (int n = t; n < N_SUP; n += 256) {
            if (tgt[n] == c) {
                const int i = atomicAdd(&cnt, 1);   // LDS atomic
                if (i < LMAX) sm.s2.lst[i] = n;
            }
        }
        __syncthreads();
        const int k = min(cnt, LMAX);
        for (int i = t; i < k; i += 256) sm.s2.rvs[i] = rinv[sm.s2.lst[i]];
        __syncthreads();

        const int col = t & 127, h = t >> 7;
        float acc = 0.f;
        for (int i = h; i < k; i += 2)
            acc = fmaf(gS[(size_t)sm.s2.lst[i] * D_DIM + d0 + col], sm.s2.rvs[i], acc);
        sm.s2.PP[h][col] = acc;
        __syncthreads();
        if (t < 128)
            Wb[(size_t)c * D_DIM + d0 + t] = f2bf(sm.s2.PP[0][t] + sm.s2.PP[1][t]);
    }
    __threadfence();
    grid.sync();
    __threadfence();

    // ---- stage 3: out = rinvF * fX @ W^T, 4-wave k-split, bf16 MFMA ----
    f32x4 acc[4] = {};
    float ssr[8];
#pragma unroll
    for (int j = 0; j < 8; ++j) ssr[j] = 0.f;

#pragma unroll
    for (int ch = 0; ch < 2; ++ch) {
        // wave-private A buffer; same-wave in-order LDS makes per-ch reuse safe
#pragma unroll
        for (int j = 0; j < 8; ++j) {
            const int f = l + 64 * j, r = f >> 5, c4 = f & 31;
            const float4 v = (ch == 0) ? ld0[j] : ld1[j];
            ssr[j] += v.x * v.x + v.y * v.y + v.z * v.z + v.w * v.w;
            ushort4 b;
            b.x = f2bf(v.x); b.y = f2bf(v.y); b.z = f2bf(v.z); b.w = f2bf(v.w);
            *reinterpret_cast<ushort4*>(&sm.s3.A[w][r * LDA + c4 * 4]) = b;
        }
#pragma unroll
        for (int ks = 0; ks < 4; ++ks) {
            const short8 a = *reinterpret_cast<const short8*>(
                &sm.s3.A[w][(l & 15) * LDA + (l >> 4) * 8 + ks * 32]);
#pragma unroll
            for (int ct = 0; ct < 4; ++ct) {
                const short8 b = *reinterpret_cast<const short8*>(
                    Wb + (size_t)(ct * 16 + (l & 15)) * D_DIM + w * KQ + ch * 128 +
                    ks * 32 + (l >> 4) * 8);
                acc[ct] = __builtin_amdgcn_mfma_f32_16x16x32_bf16(a, b, acc[ct], 0, 0, 0);
            }
        }
    }

    // in-register sumsq reduce within 32-lane halves (rows (l>>5)+2j)
#pragma unroll
    for (int off = 1; off < 32; off <<= 1)
#pragma unroll
        for (int j = 0; j < 8; ++j) ssr[j] += __shfl_xor(ssr[j], off, 64);
    if ((l & 31) == 0) {
#pragma unroll
        for (int j = 0; j < 8; ++j) SSred[w][(l >> 5) + 2 * j] = ssr[j];
    }
    __syncthreads();   // all A-reads complete before P overwrites the union

#pragma unroll
    for (int ct = 0; ct < 4; ++ct)
#pragma unroll
        for (int r = 0; r < 4; ++r)
            sm.s3.e.P[w][(l >> 4) * 4 + r][ct * 16 + (l & 15)] = acc[ct][r];
    if (t < 16)
        sm.s3.e.rinvR[t] = rsqrtf(fmaxf(
            SSred[0][t] + SSred[1][t] + SSred[2][t] + SSred[3][t], 1e-24f));
    __syncthreads();

    const int row = t >> 4, cb = (t & 15) * 4;
    const f32x4 p0 = *reinterpret_cast<const f32x4*>(&sm.s3.e.P[0][row][cb]);
    const f32x4 p1 = *reinterpret_cast<const f32x4*>(&sm.s3.e.P[1][row][cb]);
    const f32x4 p2 = *reinterpret_cast<const f32x4*>(&sm.s3.e.P[2][row][cb]);
    const f32x4 p3 = *reinterpret_cast<const f32x4*>(&sm.s3.e.P[3][row][cb]);
    const f32x4 o = (p0 + p1 + p2 + p3) * sm.s3.e.rinvR[row];
    *reinterpret_cast<f32x4*>(out + (size_t)(m0 + row) * C_CLS + cb) = o;
}

// ================= fallback path: round-4 three-kernel version =================
__global__ __launch_bounds__(256) void k_norms(const float* __restrict__ gS,
                                               float* __restrict__ rinv) {
    const int t = threadIdx.x, l = t & 63;
    const int n = blockIdx.x * 4 + (t >> 6);
    const float4* R = reinterpret_cast<const float4*>(gS + (size_t)n * D_DIM);
    float ss = 0.f;
#pragma unroll
    for (int q = 0; q < 4; ++q) {
        const float4 v = R[l + 64 * q];
        ss += v.x * v.x + v.y * v.y + v.z * v.z + v.w * v.w;
    }
#pragma unroll
    for (int off = 32; off > 0; off >>= 1) ss += __shfl_xor(ss, off, 64);
    if (l == 0) rinv[n] = rsqrtf(fmaxf(ss, 1e-24f));
}

__global__ __launch_bounds__(256) void k_classW(const float* __restrict__ gS,
                                                const int* __restrict__ tgt,
                                                const float* __restrict__ rinv,
                                                unsigned short* __restrict__ Wb) {
    const int c = blockIdx.x >> 4, d0 = (blockIdx.x & 15) * 64;
    const int t = threadIdx.x, h = t >> 6, col = t & 63;
    __shared__ int cnt; __shared__ int lst[LMAX];
    __shared__ float rvs[LMAX]; __shared__ float PP[4][64];
    if (t == 0) cnt = 0;
    __syncthreads();
    for (int n = t; n < N_SUP; n += 256)
        if (tgt[n] == c) { const int i = atomicAdd(&cnt, 1); if (i < LMAX) lst[i] = n; }
    __syncthreads();
    const int k = min(cnt, LMAX);
    for (int i = t; i < k; i += 256) rvs[i] = rinv[lst[i]];
    __syncthreads();
    float acc = 0.f;
#pragma unroll 4
    for (int i = h; i < k; i += 4)
        acc = fmaf(gS[(size_t)lst[i] * D_DIM + d0 + col], rvs[i], acc);
    PP[h][col] = acc;
    __syncthreads();
    if (t < 64) Wb[(size_t)c * D_DIM + d0 + t] = f2bf(PP[0][t] + PP[1][t] + PP[2][t] + PP[3][t]);
}

__global__ __launch_bounds__(256) void k_out_mfma(const float* __restrict__ fX,
                                                  const unsigned short* __restrict__ Wb,
                                                  float* __restrict__ out) {
    __shared__ unsigned short A[4][2][16 * LDA];
    __shared__ float P[4][16][64];
    __shared__ float SS[4][16][32];
    __shared__ float rinvR[16];
    const int t = threadIdx.x, w = t >> 6, l = t & 63;
    const int m0 = blockIdx.x * 16;
    const float* Ab = fX + (size_t)m0 * D_DIM + w * KQ;
    float4 ld0[8], ld1[8];
#pragma unroll
    for (int j = 0; j < 8; ++j) {
        const int f = l + 64 * j, r = f >> 5, c4 = f & 31;
        ld0[j] = reinterpret_cast<const float4*>(Ab + (size_t)r * D_DIM)[c4];
        ld1[j] = reinterpret_cast<const float4*>(Ab + (size_t)r * D_DIM + 128)[c4];
    }
    f32x4 acc[4] = {};
    float ssr[8];
#pragma unroll
    for (int j = 0; j < 8; ++j) ssr[j] = 0.f;
#pragma unroll
    for (int ch = 0; ch < 2; ++ch) {
#pragma unroll
        for (int j = 0; j < 8; ++j) {
            const int f = l + 64 * j, r = f >> 5, c4 = f & 31;
            const float4 v = (ch == 0) ? ld0[j] : ld1[j];
            ssr[j] += v.x * v.x + v.y * v.y + v.z * v.z + v.w * v.w;
            ushort4 b;
            b.x = f2bf(v.x); b.y = f2bf(v.y); b.z = f2bf(v.z); b.w = f2bf(v.w);
            *reinterpret_cast<ushort4*>(&A[w][ch][r * LDA + c4 * 4]) = b;
        }
#pragma unroll
        for (int ks = 0; ks < 4; ++ks) {
            const short8 a = *reinterpret_cast<const short8*>(
                &A[w][ch][(l & 15) * LDA + (l >> 4) * 8 + ks * 32]);
#pragma unroll
            for (int ct = 0; ct < 4; ++ct) {
                const short8 b = *reinterpret_cast<const short8*>(
                    Wb + (size_t)(ct * 16 + (l & 15)) * D_DIM + w * KQ + ch * 128 +
                    ks * 32 + (l >> 4) * 8);
                acc[ct] = __builtin_amdgcn_mfma_f32_16x16x32_bf16(a, b, acc[ct], 0, 0, 0);
            }
        }
    }
#pragma unroll
    for (int ct = 0; ct < 4; ++ct)
#pragma unroll
        for (int r = 0; r < 4; ++r)
            P[w][(l >> 4) * 4 + r][ct * 16 + (l & 15)] = acc[ct][r];
#pragma unroll
    for (int j = 0; j < 8; ++j) SS[w][(l >> 5) + 2 * j][l & 31] = ssr[j];
    __syncthreads();
    if (t < 64) {
        const int w2 = t >> 4, row = t & 15;
        float s = 0.f;
#pragma unroll
        for (int i = 0; i < 32; ++i) s += SS[w2][row][i];
        SS[w2][row][0] = s;
    }
    __syncthreads();
    if (t < 16)
        rinvR[t] = rsqrtf(fmaxf(SS[0][t][0] + SS[1][t][0] + SS[2][t][0] + SS[3][t][0], 1e-24f));
    __syncthreads();
    const int row = t >> 4, cb = (t & 15) * 4;
    const f32x4 p0 = *reinterpret_cast<const f32x4*>(&P[0][row][cb]);
    const f32x4 p1 = *reinterpret_cast<const f32x4*>(&P[1][row][cb]);
    const f32x4 p2 = *reinterpret_cast<const f32x4*>(&P[2][row][cb]);
    const f32x4 p3 = *reinterpret_cast<const f32x4*>(&P[3][row][cb]);
    const f32x4 o = (p0 + p1 + p2 + p3) * rinvR[row];
    *reinterpret_cast<f32x4*>(out + (size_t)(m0 + row) * C_CLS + cb) = o;
}

extern "C" void kernel_launch(void* const* d_in, const int* in_sizes, int n_in,
                              void* d_out, int out_size, void* d_ws, size_t ws_size,
                              hipStream_t stream) {
    const float* gS  = (const float*)d_in[0];
    const float* fX  = (const float*)d_in[1];
    const int*   tgt = (const int*)d_in[2];
    float* out = (float*)d_out;

    float* rinv = (float*)d_ws;                                  // 16 KB
    unsigned short* Wb = (unsigned short*)((char*)d_ws + 16384); // 128 KB bf16

    // capture-safe, deterministic host queries
    int dev = 0;
    hipGetDevice(&dev);
    int coop = 0, ncu = 0, bpc = 0;
    hipDeviceGetAttribute(&coop, hipDeviceAttributeCooperativeLaunch, dev);
    hipDeviceGetAttribute(&ncu, hipDeviceAttributeMultiprocessorCount, dev);
    hipOccupancyMaxActiveBlocksPerMultiprocessor(&bpc, (const void*)k_fused, 256, 0);

    if (coop && (long)bpc * ncu >= NBLK) {
        void* args[] = {(void*)&gS, (void*)&fX, (void*)&tgt,
                        (void*)&rinv, (void*)&Wb, (void*)&out};
        hipError_t e = hipLaunchCooperativeKernel((const void*)k_fused, dim3(NBLK),
                                                  dim3(256), args, 0, stream);
        if (e == hipSuccess) return;
    }
    // fallback: proven three-kernel path (round 4)
    hipLaunchKernelGGL(k_norms,    dim3(N_SUP / 4),  dim3(256), 0, stream, gS, rinv);
    hipLaunchKernelGGL(k_classW,   dim3(C_CLS * 16), dim3(256), 0, stream, gS, tgt, rinv, Wb);
    hipLaunchKernelGGL(k_out_mfma, dim3(M_Q / 16),   dim3(256), 0, stream, fX, Wb, out);
}

// Round 7
// 104.803 us; speedup vs baseline: 3.6291x; 3.6291x over previous
//
#include <hip/hip_runtime.h>
#include <hip/hip_bf16.h>

#define D_DIM 1024
#define C_CLS 64
#define N_SUP 4096
#define M_Q   8192
#define LMAX  320
#define LDA   136
#define KQ    256

typedef __attribute__((ext_vector_type(8))) short short8;
typedef __attribute__((ext_vector_type(4))) float f32x4;

__device__ inline unsigned short f2bf(float x) {
    __hip_bfloat16 h = __float2bfloat16(x);
    return __builtin_bit_cast(unsigned short, h);
}

// ---- K1: rinv[n] = 1/||gS[n]||. 1024 blocks x 4 waves, 1 row/wave. ----
__global__ __launch_bounds__(256) void k_norms(const float* __restrict__ gS,
                                               float* __restrict__ rinv) {
    const int t = threadIdx.x, l = t & 63;
    const int n = blockIdx.x * 4 + (t >> 6);
    const float4* R = reinterpret_cast<const float4*>(gS + (size_t)n * D_DIM);
    float ss = 0.f;
#pragma unroll
    for (int q = 0; q < 4; ++q) {
        const float4 v = R[l + 64 * q];
        ss += v.x * v.x + v.y * v.y + v.z * v.z + v.w * v.w;
    }
#pragma unroll
    for (int off = 32; off > 0; off >>= 1) ss += __shfl_xor(ss, off, 64);
    if (l == 0) rinv[n] = rsqrtf(fmaxf(ss, 1e-24f));
}

// ---- K2: Wb[c][d] = sum_{tgt[n]==c} gS[n][d]*rinv[n].  1024 blocks =
// 64 classes x 16 chunks of 64 cols; 4 waves take every 4th member.
// Gather manually 4-deep pipelined (4 independent loads in flight). ----
__global__ __launch_bounds__(256) void k_classW(const float* __restrict__ gS,
                                                const int* __restrict__ tgt,
                                                const float* __restrict__ rinv,
                                                unsigned short* __restrict__ Wb) {
    const int c = blockIdx.x >> 4, d0 = (blockIdx.x & 15) * 64;
    const int t = threadIdx.x, h = t >> 6, col = t & 63;
    __shared__ int cnt; __shared__ int lst[LMAX];
    __shared__ float rvs[LMAX]; __shared__ float PP[4][64];
    if (t == 0) cnt = 0;
    __syncthreads();
    const int4* T4 = reinterpret_cast<const int4*>(tgt);
    for (int q = t; q < N_SUP / 4; q += 256) {
        const int4 v4 = T4[q];
        const int base = q * 4;
        if (v4.x == c) { const int i = atomicAdd(&cnt, 1); if (i < LMAX) lst[i] = base; }
        if (v4.y == c) { const int i = atomicAdd(&cnt, 1); if (i < LMAX) lst[i] = base + 1; }
        if (v4.z == c) { const int i = atomicAdd(&cnt, 1); if (i < LMAX) lst[i] = base + 2; }
        if (v4.w == c) { const int i = atomicAdd(&cnt, 1); if (i < LMAX) lst[i] = base + 3; }
    }
    __syncthreads();
    const int k = min(cnt, LMAX);
    for (int i = t; i < k; i += 256) rvs[i] = rinv[lst[i]];
    __syncthreads();

    float acc = 0.f;
    int i = h;
    for (; i + 12 < k; i += 16) {   // 4 independent loads per iteration
        const float v0 = gS[(size_t)lst[i] * D_DIM + d0 + col];
        const float v1 = gS[(size_t)lst[i + 4] * D_DIM + d0 + col];
        const float v2 = gS[(size_t)lst[i + 8] * D_DIM + d0 + col];
        const float v3 = gS[(size_t)lst[i + 12] * D_DIM + d0 + col];
        acc = fmaf(v0, rvs[i], acc);
        acc = fmaf(v1, rvs[i + 4], acc);
        acc = fmaf(v2, rvs[i + 8], acc);
        acc = fmaf(v3, rvs[i + 12], acc);
    }
    for (; i < k; i += 4)
        acc = fmaf(gS[(size_t)lst[i] * D_DIM + d0 + col], rvs[i], acc);

    PP[h][col] = acc;
    __syncthreads();
    if (t < 64)
        Wb[(size_t)c * D_DIM + d0 + t] = f2bf(PP[0][t] + PP[1][t] + PP[2][t] + PP[3][t]);
}

// ---- K3: out[m,c] = rinvF[m] * sum_k fX[m,k]*W[c,k]  (bf16 MFMA) ----
// 512 blocks x 4 waves; block owns 16 rows; wave w owns k-quarter.
// Single wave-private A-buffer reused across both 128-col chunks (same-wave
// DS ordering makes reuse safe). LDS ~35 KB -> 4 blocks/CU capacity.
__global__ __launch_bounds__(256, 4) void k_out_mfma(const float* __restrict__ fX,
                                                     const unsigned short* __restrict__ Wb,
                                                     float* __restrict__ out) {
    __shared__ unsigned short A[4][16 * LDA];  // 17.0 KB, wave-private
    __shared__ float P[4][16][68];             // 17.4 KB, padded stride
    __shared__ float SSred[4][16];
    __shared__ float rinvR[16];

    const int t = threadIdx.x, w = t >> 6, l = t & 63;
    const int m0 = blockIdx.x * 16;
    const float* Ab = fX + (size_t)m0 * D_DIM + w * KQ;

    float4 ld[8];
#pragma unroll
    for (int j = 0; j < 8; ++j) {
        const int f = l + 64 * j, r = f >> 5, c4 = f & 31;
        ld[j] = reinterpret_cast<const float4*>(Ab + (size_t)r * D_DIM)[c4];
    }

    f32x4 acc[4] = {};
    float ssr[8];
#pragma unroll
    for (int j = 0; j < 8; ++j) ssr[j] = 0.f;

#pragma unroll
    for (int ch = 0; ch < 2; ++ch) {
        // convert chunk -> wave-private A; accumulate sumsq
#pragma unroll
        for (int j = 0; j < 8; ++j) {
            const int f = l + 64 * j, r = f >> 5, c4 = f & 31;
            const float4 v = ld[j];
            ssr[j] += v.x * v.x + v.y * v.y + v.z * v.z + v.w * v.w;
            ushort4 b;
            b.x = f2bf(v.x); b.y = f2bf(v.y); b.z = f2bf(v.z); b.w = f2bf(v.w);
            *reinterpret_cast<ushort4*>(&A[w][r * LDA + c4 * 4]) = b;
        }
        // issue next chunk's globals; they fly under this chunk's MFMA phase
        if (ch == 0) {
#pragma unroll
            for (int j = 0; j < 8; ++j) {
                const int f = l + 64 * j, r = f >> 5, c4 = f & 31;
                ld[j] = reinterpret_cast<const float4*>(Ab + (size_t)r * D_DIM + 128)[c4];
            }
        }
#pragma unroll
        for (int ks = 0; ks < 4; ++ks) {
            const short8 a = *reinterpret_cast<const short8*>(
                &A[w][(l & 15) * LDA + (l >> 4) * 8 + ks * 32]);
#pragma unroll
            for (int ct = 0; ct < 4; ++ct) {
                const short8 b = *reinterpret_cast<const short8*>(
                    Wb + (size_t)(ct * 16 + (l & 15)) * D_DIM + w * KQ + ch * 128 +
                    ks * 32 + (l >> 4) * 8);
                acc[ct] = __builtin_amdgcn_mfma_f32_16x16x32_bf16(a, b, acc[ct], 0, 0, 0);
            }
        }
    }

    // in-register sumsq reduce across the 32 col-groups (stays in 32-lane halves)
#pragma unroll
    for (int off = 1; off < 32; off <<= 1)
#pragma unroll
        for (int j = 0; j < 8; ++j) ssr[j] += __shfl_xor(ssr[j], off, 64);
    if ((l & 31) == 0) {
#pragma unroll
        for (int j = 0; j < 8; ++j) SSred[w][(l >> 5) + 2 * j] = ssr[j];
    }

    // stash per-wave MFMA partials (stride 68: write groups land 2-way = free)
#pragma unroll
    for (int ct = 0; ct < 4; ++ct)
#pragma unroll
        for (int r = 0; r < 4; ++r)
            P[w][(l >> 4) * 4 + r][ct * 16 + (l & 15)] = acc[ct][r];
    __syncthreads();
    if (t < 16)
        rinvR[t] = rsqrtf(fmaxf(
            SSred[0][t] + SSred[1][t] + SSred[2][t] + SSred[3][t], 1e-24f));
    __syncthreads();

    const int row = t >> 4, cb = (t & 15) * 4;
    const float* Pr = &P[0][row][cb];
    const f32x4 p0 = *reinterpret_cast<const f32x4*>(Pr);
    const f32x4 p1 = *reinterpret_cast<const f32x4*>(Pr + 16 * 68);
    const f32x4 p2 = *reinterpret_cast<const f32x4*>(Pr + 32 * 68);
    const f32x4 p3 = *reinterpret_cast<const f32x4*>(Pr + 48 * 68);
    const f32x4 o = (p0 + p1 + p2 + p3) * rinvR[row];
    *reinterpret_cast<f32x4*>(out + (size_t)(m0 + row) * C_CLS + cb) = o;
}

extern "C" void kernel_launch(void* const* d_in, const int* in_sizes, int n_in,
                              void* d_out, int out_size, void* d_ws, size_t ws_size,
                              hipStream_t stream) {
    const float* gS  = (const float*)d_in[0];
    const float* fX  = (const float*)d_in[1];
    const int*   tgt = (const int*)d_in[2];
    float* out = (float*)d_out;

    float* rinv = (float*)d_ws;                                  // 16 KB
    unsigned short* Wb = (unsigned short*)((char*)d_ws + 16384); // 128 KB bf16

    hipLaunchKernelGGL(k_norms,    dim3(N_SUP / 4),  dim3(256), 0, stream, gS, rinv);
    hipLaunchKernelGGL(k_classW,   dim3(C_CLS * 16), dim3(256), 0, stream, gS, tgt, rinv, Wb);
    hipLaunchKernelGGL(k_out_mfma, dim3(M_Q / 16),   dim3(256), 0, stream, fX, Wb, out);
}